// Round 12
// baseline (67.291 us; speedup 1.0000x reference)
//
#include <hip/hip_runtime.h>
#include <hip/hip_bf16.h>

typedef __bf16 bf16x8 __attribute__((ext_vector_type(8)));
typedef float  f32x4  __attribute__((ext_vector_type(4)));

// Async global->LDS DMA (no register result: compiler cannot re-roll/sink it).
__device__ __forceinline__ void dma16(const float* g, float* l) {
    typedef const __attribute__((address_space(1))) unsigned int* gp_t;
    typedef __attribute__((address_space(3))) unsigned int*       lp_t;
    __builtin_amdgcn_global_load_lds((gp_t)(const void*)g, (lp_t)(void*)l, 16, 0, 0);
}

// 2-way SHARER FUSION on the r11 DMA-ring. rowi[s][c] = c%16+16s, so columns
// cp and cp+32 consume IDENTICAL A k-blocks: one block (8 waves, 512 thr)
// computes both -> each A fragment converted once feeds 2 sharers' B (16
// MFMA/step) -> A cache traffic 512->256 MB. Rounds 3/6/9/11 all pinned at
// ~12-13 TB/s aggregate L2/L3 service; traffic drops 680->424 MB.
// Mechanism (r9/r11-proven): per-wave private depth-2 LDS ring, DMA with
// pre-swizzled source (linear dest, XOR rr<<4 on read, 0 conflicts), ZERO
// main-loop barriers, counted vmcnt (never 0 mid-loop). Step order mt-outer/
// kb-inner: acc only [2][4] (32 VGPR); C stores spread at kb==3 steps (32
// dwords) so the 6-bit vmcnt counter never saturates. In-order retirement:
// the 2 steps after a store-step wait vmcnt(36)=32 stores+4 loads younger.
// B: 8 blocks (2 sharers x 4 kb, 64 KB bf16) staged once, read per-MFMA.
// LDS 128 KB -> 1 block/CU; grid 256 = exactly 1/CU, one generation, no tail.
__global__ __launch_bounds__(512, 2) void sparse_linear_kernel(
    const float* __restrict__ A, const float* __restrict__ Bd,
    const int* __restrict__ rowi, const int* __restrict__ di,
    float* __restrict__ C)
{
    __shared__ __align__(16) float Aring[8][2][16 * 64];       // 64 KB
    __shared__ __align__(16) unsigned short Bt[8 * 64 * 64];   // 64 KB [j*4+kb][n][k]
    char* BtB = (char*)Bt;

    const int bid = blockIdx.x;
    const int cp  = bid & 31;          // sharer pair: columns cp and cp+32
    const int grp = bid >> 5;          // 0..7 -> rows [grp*1024, +1024)
    const int t    = threadIdx.x;
    const int lane = t & 63;
    const int w    = t >> 6;           // 0..7

    int koff[4], dsj[2][4];
    #pragma unroll
    for (int s = 0; s < 4; ++s) {
        koff[s] = rowi[s * 64 + cp] * 64;          // same k-block for both sharers
        dsj[0][s] = di[s * 64 + cp];
        dsj[1][s] = di[s * 64 + cp + 32];
    }

    const long wrow0 = (long)grp * 1024 + w * 64;  // + q*512 + mt*16

    // DMA one 16x64 step-tile into ring slot. Flat step st: q=st>>4,
    // mt=(st>>2)&3, kb=st&3. Source pre-swizzled (XOR rr<<4), dest linear.
    auto dmaA = [&](int st, int slot) {
        if (st > 31) st = 31;                      // tail clamp (redundant, unread)
        const int q = st >> 4, mt = (st >> 2) & 3, kb = st & 3;
        float* slotp = &Aring[w][slot][0];
        #pragma unroll
        for (int i = 0; i < 4; ++i) {
            const int rr  = i * 4 + (lane >> 4);
            const int kfl = (((lane & 15) * 16) ^ (rr << 4)) >> 2;
            const float* g = A + (wrow0 + q * 512 + mt * 16 + rr) * 4096 + koff[kb] + kfl;
            dma16(g, slotp + i * 256);
        }
    };

    // ---- prologue: fill slots 0,1 = steps 0,1 ----
    dmaA(0, 0);
    dmaA(1, 1);

    // ---- stage B once: thread t -> sharer j, k-block kb, column n ----
    {
        const int jj = t >> 6;                     // 0..7: j = jj>>2, kb = jj&3
        const int n  = t & 63;
        const float* Bg = Bd + (long)dsj[jj >> 2][jj & 3] * 64 + n;   // row stride 16384
        char* dst = BtB + jj * 8192 + n * 128;
        const int sw = (n & 7) << 4;
        #pragma unroll
        for (int k4 = 0; k4 < 16; ++k4) {
            union { ushort4 u4; __bf16 e[4]; } pk;
            pk.e[0] = (__bf16)Bg[(long)(4 * k4 + 0) * 16384];
            pk.e[1] = (__bf16)Bg[(long)(4 * k4 + 1) * 16384];
            pk.e[2] = (__bf16)Bg[(long)(4 * k4 + 2) * 16384];
            pk.e[3] = (__bf16)Bg[(long)(4 * k4 + 3) * 16384];
            *(ushort4*)(dst + ((8 * k4) ^ sw)) = pk.u4;
        }
    }
    __syncthreads();   // the only barrier (drains prologue DMAs + B writes)

    f32x4 acc[2][4];   // [j][n2] for the current mt only
    #pragma unroll
    for (int j = 0; j < 2; ++j)
        #pragma unroll
        for (int n2 = 0; n2 < 4; ++n2) acc[j][n2] = f32x4{0.f, 0.f, 0.f, 0.f};

    #pragma unroll 1
    for (int q = 0; q < 2; ++q) {
        #pragma unroll
        for (int local = 0; local < 16; ++local) {
            const int st = q * 16 + local;
            const int mt = local >> 2, kb = local & 3;
            const int slot = st & 1;

            // Counted wait (in-order): after a store-step, 32 stores + 4 loads
            // are younger than the target slot's DMAs -> 36; else 4.
            if ((st & 3) <= 1 && st >= 4) asm volatile("s_waitcnt vmcnt(36)" ::: "memory");
            else                          asm volatile("s_waitcnt vmcnt(4)"  ::: "memory");
            __builtin_amdgcn_sched_barrier(0);

            // A fragment: swizzled read from ring slot; convert fp32->bf16
            const char* ab = (const char*)&Aring[w][slot][0];
            const int r   = lane & 15;
            const int q32 = (lane >> 4) * 32;
            f32x4 a0 = *(const f32x4*)(ab + r * 256 + ((q32)            ^ (r << 4)));
            f32x4 a1 = *(const f32x4*)(ab + r * 256 + ((q32 + 16)       ^ (r << 4)));
            f32x4 a2 = *(const f32x4*)(ab + r * 256 + ((128 + q32)      ^ (r << 4)));
            f32x4 a3 = *(const f32x4*)(ab + r * 256 + ((128 + q32 + 16) ^ (r << 4)));
            union { bf16x8 v; __bf16 e[8]; } af0, af1;
            #pragma unroll
            for (int i = 0; i < 4; ++i) {
                af0.e[i]     = (__bf16)a0[i];
                af0.e[i + 4] = (__bf16)a1[i];
                af1.e[i]     = (__bf16)a2[i];
                af1.e[i + 4] = (__bf16)a3[i];
            }

            // 16 MFMAs: one A fragment x 2 sharers x 2 kh x 4 n2
            __builtin_amdgcn_s_setprio(1);
            #pragma unroll
            for (int kh = 0; kh < 2; ++kh) {
                const bf16x8 afv = kh ? af1.v : af0.v;
                #pragma unroll
                for (int j = 0; j < 2; ++j) {
                    const char* bb = BtB + (j * 4 + kb) * 8192;
                    #pragma unroll
                    for (int n2 = 0; n2 < 4; ++n2) {
                        const int nr = n2 * 16 + (lane & 15);
                        bf16x8 bf = *(const bf16x8*)(bb + nr * 128 +
                                    ((kh * 64 + (lane >> 4) * 16) ^ ((nr & 7) << 4)));
                        acc[j][n2] = __builtin_amdgcn_mfma_f32_16x16x32_bf16(
                            afv, bf, acc[j][n2], 0, 0, 0);
                    }
                }
            }
            __builtin_amdgcn_s_setprio(0);

            // Refill this slot for step st+2 (every step; tail clamped).
            dmaA(st + 2, slot);

            // End of mt (kb==3): store this m-tile's C for both sharers.
            if (kb == 3) {
                __builtin_amdgcn_sched_barrier(0);
                const long crow0 = wrow0 + q * 512 + mt * 16 + (lane >> 4) * 4;
                #pragma unroll
                for (int j = 0; j < 2; ++j) {
                    const long col0 = (long)(cp + 32 * j) * 64 + (lane & 15);
                    #pragma unroll
                    for (int n2 = 0; n2 < 4; ++n2) {
                        #pragma unroll
                        for (int v = 0; v < 4; ++v)
                            __builtin_nontemporal_store(acc[j][n2][v],
                                &C[(crow0 + v) * 4096 + col0 + n2 * 16]);
                        acc[j][n2] = f32x4{0.f, 0.f, 0.f, 0.f};
                    }
                }
                __builtin_amdgcn_sched_barrier(0);
            }
        }
    }

    asm volatile("s_waitcnt vmcnt(0)" ::: "memory");   // drain tail DMAs/stores
}

extern "C" void kernel_launch(void* const* d_in, const int* in_sizes, int n_in,
                              void* d_out, int out_size, void* d_ws, size_t ws_size,
                              hipStream_t stream) {
    const float* A    = (const float*)d_in[0];
    const float* Bd   = (const float*)d_in[1];
    const int*   rowi = (const int*)d_in[2];
    const int*   di   = (const int*)d_in[3];
    float*       C    = (float*)d_out;

    dim3 grid(8 * 32);    // 8 row-groups x 32 sharer-pairs = 256 blocks = 1/CU
    dim3 block(512);
    hipLaunchKernelGGL(sparse_linear_kernel, grid, block, 0, stream,
                       A, Bd, rowi, di, C);
}